// Round 7
// baseline (65.128 us; speedup 1.0000x reference)
//
#include <hip/hip_runtime.h>

// Involution fused kernels for MI355X (gfx950).
// x: (4,256,56,56) f32, w1: (64,256), bn(64), w2: (784,64), b2: (784)
// out: (4,256,56,56) f32
// ws: ybf16 [4][3136][64] | wprep bf16 [16][64][64] | b2pad f32 [16][64] | w1T f32 [256][64]

#define HW    3136
#define WIDE  56
#define C_IN  256
#define CR    64
#define GC    16
#define KK    49
#define BN_EPS 1e-5f

typedef __attribute__((ext_vector_type(8))) short short8;
typedef __attribute__((ext_vector_type(4))) float f32x4;
typedef __attribute__((ext_vector_type(2))) unsigned int u32x2;

__device__ __forceinline__ unsigned short f2bf(float f) {
    unsigned u = __float_as_uint(f);
    return (unsigned short)((u + 0x7FFFu + ((u >> 16) & 1u)) >> 16);   // RNE
}

// ---- Prep: w1T[c][o] f32; wprep[g][k][c] bf16 (k>=49 zero); b2pad[g][k] f32 ----
__global__ __launch_bounds__(256) void prep_kernel(
    const float* __restrict__ w1, const float* __restrict__ w2,
    const float* __restrict__ b2,
    float* __restrict__ w1T, unsigned short* __restrict__ wprep,
    float* __restrict__ b2pad)
{
    const int t = blockIdx.x * 256 + threadIdx.x;   // 0..65535
    if (t < 16384) {                                // w1T: c=t>>6, o=t&63
        const int c = t >> 6, o = t & 63;
        w1T[c * 64 + o] = w1[o * C_IN + c];
    }
    {                                               // wprep: g=t>>12, k=(t>>6)&63, c=t&63
        const int g = t >> 12, k = (t >> 6) & 63, c = t & 63;
        wprep[t] = (k < KK) ? f2bf(w2[(size_t)(g * KK + k) * CR + c]) : (unsigned short)0;
    }
    if (t < 1024) {                                 // b2pad
        const int g = t >> 6, k = t & 63;
        b2pad[t] = (k < KK) ? b2[g * KK + k] : 0.f;
    }
}

// ---- Kernel 1: y = relu(bn(w1 @ x)) -> bf16, layout [b][px][c] ----
// grid (196 px-tiles, 4 og-quads) x 256 thr (exact R5 known-good config).
__global__ __launch_bounds__(256) void conv1_bn_relu(
    const float* __restrict__ x, const float* __restrict__ w1T,
    const float* __restrict__ gamma, const float* __restrict__ beta,
    const float* __restrict__ mean, const float* __restrict__ var,
    unsigned short* __restrict__ ybf)
{
    const int t    = threadIdx.x;
    const int lane = t & 63;
    const int og   = __builtin_amdgcn_readfirstlane(blockIdx.y * 4 + (t >> 6)); // 0..15
    const int tile = blockIdx.x;          // 0..195
    const int b    = tile / 49;
    const int hw   = (tile - b * 49) * 64 + lane;

    const float* __restrict__ xb = x + (size_t)b * C_IN * HW + hw;

    float acc[4] = {0.f, 0.f, 0.f, 0.f};
#pragma unroll 8
    for (int c = 0; c < C_IN; ++c) {
        const float xv = xb[(size_t)c * HW];
        const f32x4 wv = *(const f32x4*)(w1T + c * 64 + og * 4);   // uniform -> s_load_dwordx4
#pragma unroll
        for (int u = 0; u < 4; ++u) acc[u] += wv[u] * xv;
    }

    unsigned short o4[4];
#pragma unroll
    for (int u = 0; u < 4; ++u) {
        const int o = og * 4 + u;
        const float sc = gamma[o] * rsqrtf(var[o] + BN_EPS);
        const float sh = beta[o] - mean[o] * sc;
        o4[u] = f2bf(fmaxf(acc[u] * sc + sh, 0.f));
    }
    u32x2 pack;
    pack.x = (unsigned)o4[0] | ((unsigned)o4[1] << 16);
    pack.y = (unsigned)o4[2] | ((unsigned)o4[3] << 16);
    *(u32x2*)(ybf + ((size_t)(b * HW + hw)) * 64 + og * 4) = pack;
}

// ---- Kernel 2: MFMA conv2 + vectorized involution. 1 wave per block. ----
// Block = (b, g, 64-px tile), 64 threads (R5 structure).
// Phase 1: 32x mfma_f32_16x16x32_bf16 -> kw[49 taps][64 px] in LDS
//          (bias added, OOB taps zeroed). kw_lds shrunk to [50][64]
//          (12.8 KB -> 12 blocks/CU, was 10).
// Phase 2: thread = (pg -> 4 px, cq -> 4 ch). ROW DOUBLE-BUFFER: row i+1's
//          12 f32x4 loads are issued before row i's FMA block -> 12 loads
//          in flight per thread (was 3). All indexing compile-time after
//          full unroll. Garbage edge elements only multiply kw==0.
__global__ __launch_bounds__(64) void conv2_involution(
    const float* __restrict__ x, const unsigned short* __restrict__ ybf,
    const unsigned short* __restrict__ wprep, const float* __restrict__ b2pad,
    float* __restrict__ out)
{
    __shared__ float kw_lds[50 * 64];   // [tap][px], 12.8 KB

    const int tid  = threadIdx.x;
    const int l15  = tid & 15;
    const int lg   = tid >> 4;
    const int tile = blockIdx.x;                 // 0..48
    const int g    = blockIdx.y & 15;
    const int b    = blockIdx.y >> 4;

    // ---- Phase 1: kw = W2g @ y  (per-pixel taps, all 4 px-quadrants) ----
    {
        short8 Bf[4][2], Af[4][2];
#pragma unroll
        for (int ct = 0; ct < 4; ++ct) {
            const int hwp = tile * 64 + ct * 16 + l15;
            const unsigned short* yb = ybf + ((size_t)(b * HW + hwp)) * 64 + lg * 8;
            Bf[ct][0] = *(const short8*)(yb);
            Bf[ct][1] = *(const short8*)(yb + 32);
        }
#pragma unroll
        for (int rt = 0; rt < 4; ++rt) {
            const unsigned short* ar = wprep + g * 4096 + (rt * 16 + l15) * 64 + lg * 8;
            Af[rt][0] = *(const short8*)(ar);
            Af[rt][1] = *(const short8*)(ar + 32);
        }
        f32x4 acc[4][4];
#pragma unroll
        for (int ct = 0; ct < 4; ++ct)
#pragma unroll
            for (int rt = 0; rt < 4; ++rt) {
                acc[ct][rt] = (f32x4){0.f, 0.f, 0.f, 0.f};
                acc[ct][rt] = __builtin_amdgcn_mfma_f32_16x16x32_bf16(Af[rt][0], Bf[ct][0], acc[ct][rt], 0, 0, 0);
                acc[ct][rt] = __builtin_amdgcn_mfma_f32_16x16x32_bf16(Af[rt][1], Bf[ct][1], acc[ct][rt], 0, 0, 0);
            }

        float bias[4][4];
#pragma unroll
        for (int rt = 0; rt < 4; ++rt)
#pragma unroll
            for (int r = 0; r < 4; ++r)
                bias[rt][r] = b2pad[g * 64 + rt * 16 + lg * 4 + r];

#pragma unroll
        for (int ct = 0; ct < 4; ++ct) {
            const int pxc = ct * 16 + l15;
            const int hwp = tile * 64 + pxc;
            const int hp  = hwp / WIDE;
            const int wp  = hwp - hp * WIDE;
#pragma unroll
            for (int rt = 0; rt < 4; ++rt)
#pragma unroll
                for (int r = 0; r < 4; ++r) {
                    const int k = rt * 16 + lg * 4 + r;
                    if (k < KK) {
                        const float val = acc[ct][rt][r] + bias[rt][r];
                        const int i7 = k / 7, j7 = k - i7 * 7;
                        const int rr = hp + i7 - 3, cc = wp + j7 - 3;
                        const bool valid = (rr >= 0) & (rr < WIDE) &
                                           (cc >= 0) & (cc < WIDE);
                        kw_lds[k * 64 + pxc] = valid ? val : 0.f;
                    }
                }
        }
    }
    __syncthreads();

    // ---- Phase 2: involution, 4 px x 4 ch per thread, row-double-buffered ----
    const int pg   = tid & 15;
    const int cq   = tid >> 4;
    const int hw4  = tile * 64 + pg * 4;         // 4-aligned flat pixel base
    const int hrow = hw4 / WIDE;
    const int hcol = hw4 - hrow * WIDE;          // 4-aligned (56 % 4 == 0)

    const float* bp[4];
#pragma unroll
    for (int c = 0; c < 4; ++c)
        bp[c] = x + ((size_t)b * C_IN + g * GC + cq * 4 + c) * HW;

    const float* __restrict__ kwb = kw_lds + pg * 4;

    float acc[4][4];   // [ch][px]
#pragma unroll
    for (int c = 0; c < 4; ++c)
#pragma unroll
        for (int p = 0; p < 4; ++p) acc[c][p] = 0.f;

    f32x4 buf[2][4][3];
    auto loadrow = [&](int i, int s) {
        const int rc    = min(max(hrow + i - 3, 0), WIDE - 1);  // v_med3
        const int basef = rc * WIDE + hcol;
        const int i0 = max(basef - 4, 0);
        const int i2 = min(basef + 4, HW - 4);
#pragma unroll
        for (int c = 0; c < 4; ++c) {
            buf[s][c][0] = *(const f32x4*)(bp[c] + i0);
            buf[s][c][1] = *(const f32x4*)(bp[c] + basef);
            buf[s][c][2] = *(const f32x4*)(bp[c] + i2);
        }
    };

    loadrow(0, 0);
#pragma unroll
    for (int i = 0; i < 7; ++i) {
        const int s = i & 1;
        if (i < 6) loadrow(i + 1, s ^ 1);        // next row's 12 loads in flight

        float win[4][12];
#pragma unroll
        for (int c = 0; c < 4; ++c)
#pragma unroll
            for (int e = 0; e < 4; ++e) {
                win[c][e]     = buf[s][c][0][e];
                win[c][e + 4] = buf[s][c][1][e];
                win[c][e + 8] = buf[s][c][2][e];
            }
#pragma unroll
        for (int jj = 0; jj < 7; ++jj) {
            const f32x4 kw4 = *(const f32x4*)&kwb[(i * 7 + jj) * 64];
#pragma unroll
            for (int c = 0; c < 4; ++c)
#pragma unroll
                for (int p = 0; p < 4; ++p)
                    acc[c][p] += kw4[p] * win[c][p + jj + 1];   // e = 4+(p+jj-3)
        }
    }

#pragma unroll
    for (int c = 0; c < 4; ++c) {
        f32x4 st;
#pragma unroll
        for (int p = 0; p < 4; ++p) st[p] = acc[c][p];
        *(f32x4*)(out + ((size_t)b * C_IN + g * GC + cq * 4 + c) * HW + hw4) = st;
    }
}

extern "C" void kernel_launch(void* const* d_in, const int* in_sizes, int n_in,
                              void* d_out, int out_size, void* d_ws, size_t ws_size,
                              hipStream_t stream) {
    const float* x     = (const float*)d_in[0];
    const float* w1    = (const float*)d_in[1];
    const float* gamma = (const float*)d_in[2];
    const float* beta  = (const float*)d_in[3];
    const float* mean  = (const float*)d_in[4];
    const float* var   = (const float*)d_in[5];
    const float* w2    = (const float*)d_in[6];
    const float* b2    = (const float*)d_in[7];
    float* out = (float*)d_out;

    char* ws = (char*)d_ws;
    unsigned short* ybf   = (unsigned short*)(ws);             // 1,605,632 B
    unsigned short* wprep = (unsigned short*)(ws + 1605632);   //   131,072 B
    float*          b2pad = (float*)(ws + 1736704);            //     4,096 B
    float*          w1T   = (float*)(ws + 1740800);            //    65,536 B

    prep_kernel<<<dim3(256), dim3(256), 0, stream>>>(w1, w2, b2, w1T, wprep, b2pad);
    conv1_bn_relu<<<dim3(196, 4), dim3(256), 0, stream>>>(x, w1T, gamma, beta, mean, var, ybf);
    conv2_involution<<<dim3(49, 64), dim3(64), 0, stream>>>(x, ybf, wprep, b2pad, out);
}